// Round 16
// baseline (738.189 us; speedup 1.0000x reference)
//
#include <hip/hip_runtime.h>
#include <math.h>

typedef short short8 __attribute__((ext_vector_type(8)));
typedef _Float16 half8 __attribute__((ext_vector_type(8)));
typedef float floatx4 __attribute__((ext_vector_type(4)));

#define Bb 64
#define Ss 512
#define Hh 512
#define DFF 2048
#define HOPS 6
#define BS (Bb*Ss)          // 32768 positions
#define PS 1048576          // weight plane stride (elems)
#define BUFP 16384          // paired A stage buffer (2 k-slabs x 8 KB)

// ---------------- fp16 pack helpers ---------------------------------------
// ALL operands single fp16 plane. Error ledger (independent terms,
// quadrature-combined, vs observed floor absmax=0.0078):
//   h-rounding (R7):   ~3.4e-4  -- accepted, absmax 0.0039->0.0078
//   W2-rounding (R10): ~3.4e-4  -- accepted, absmax unchanged
//   W1-rounding (R11): ~2.0e-4  -- accepted, absmax unchanged
// R14 lesson: direct-VGPR loads (no LDS DMA) regressed 30% -- the
// global_load_lds fire-and-forget DMA + counted vmcnt is the enabler.
// R16: k-steps processed in PAIRS (one rendezvous per 32 MFMA/wave, was 16).
__device__ inline unsigned short f16u(float v) {
  _Float16 h = (_Float16)v;
  union { _Float16 h; unsigned short u; } c; c.h = h; return c.u;
}
__device__ inline void split8_store1(const float* xs, unsigned short* dst) {
  unsigned q[4];
#pragma unroll
  for (int j = 0; j < 4; ++j)
    q[j] = (unsigned)f16u(xs[2*j]) | ((unsigned)f16u(xs[2*j+1]) << 16);
  *(int4*)dst = make_int4(q[0], q[1], q[2], q[3]);
}

// ---------------- async global->LDS 16B helper -----------------------------
__device__ __forceinline__ void gload16(const void* g, void* l) {
  __builtin_amdgcn_global_load_lds(
      (const __attribute__((address_space(1))) void*)g,
      (__attribute__((address_space(3))) void*)l, 16, 0, 0);
}

// ---------------- weight pre-split into fragment-linear fp16 planes -------
__global__ __launch_bounds__(256) void prep_kernel(
    const float* __restrict__ w, unsigned short* __restrict__ wf,
    int K32, int NTOT, int N)
{
  int id = blockIdx.x * 256 + threadIdx.x;      // one per (k0,NT,lane)
  if (id >= K32 * NTOT * 64) return;
  int l  = id & 63;
  int NT = (id >> 6) % NTOT;
  int k0 = id / (64 * NTOT);
  int n  = NT * 16 + (l & 15);
  int kb = k0 * 32 + 8 * (l >> 4);
  float xs[8];
#pragma unroll
  for (int j = 0; j < 8; ++j) xs[j] = w[(size_t)(kb + j) * N + n];
  split8_store1(xs, wf + (size_t)id * 8);
}

// ---------------- parallel compaction (order-free, outputs invariant) ------
__global__ __launch_bounds__(1024) void compact_kernel(
    const float* __restrict__ halting, int* __restrict__ idx,
    int* __restrict__ cnt, int tzero)
{
  __shared__ int wsum[16];
  __shared__ int wbase[16];
  __shared__ int s_base;
  int tid = threadIdx.x;
  int lane = tid & 63, wid = tid >> 6;
  int pos = blockIdx.x * 1024 + tid;
  int flag = tzero ? 1 : ((halting[pos] < 1.0f) ? 1 : 0);
  unsigned long long m = __ballot(flag);
  int pre = __popcll(m & ((1ull << lane) - 1ull));
  if (lane == 0) wsum[wid] = __popcll(m);
  __syncthreads();
  if (tid == 0) {
    int a = 0;
#pragma unroll
    for (int i = 0; i < 16; ++i) { wbase[i] = a; a += wsum[i]; }
    s_base = (a > 0) ? atomicAdd(cnt, a) : 0;
  }
  __syncthreads();
  if (flag) idx[s_base + wbase[wid] + pre] = pos;
}

// ---------------- halting / p kernel (pure fp32) ---------------------------
__global__ __launch_bounds__(256) void halt_kernel(
    const float* __restrict__ st, const float* __restrict__ te,
    const float* __restrict__ pe_t, const float* __restrict__ wp,
    const float* __restrict__ bp, float* __restrict__ halting,
    float* __restrict__ remainders, float* __restrict__ n_updates,
    float* __restrict__ uw_c, const int* __restrict__ idxbuf,
    const int* __restrict__ cntp, int tzero)
{
  int cnt = *cntp;
  int i = blockIdx.x * 4 + (threadIdx.x >> 6);
  if (i >= cnt) return;
  int lane = threadIdx.x & 63;
  int pos = idxbuf[i];
  int s = pos & (Ss - 1);
  const float4* stv = (const float4*)(st + (size_t)pos * Hh);
  const float4* tev = (const float4*)(te + (size_t)s * Hh);
  const float4* pev = (const float4*)pe_t;
  const float4* wpv = (const float4*)wp;
  float sum = 0.f;
#pragma unroll
  for (int j = 0; j < 2; ++j) {
    int idx = lane + j * 64;
    float4 a = stv[idx], b = tev[idx], c = pev[idx], w = wpv[idx];
    sum += (a.x + b.x + c.x) * w.x + (a.y + b.y + c.y) * w.y +
           (a.z + b.z + c.z) * w.z + (a.w + b.w + c.w) * w.w;
  }
#pragma unroll
  for (int off = 32; off > 0; off >>= 1) sum += __shfl_xor(sum, off, 64);
  if (lane == 0) {
    float y = sum + bp[0];
    float p = 1.0f / (1.0f + expf(-y));
    const float THRESH = 1.0f - 0.1f;
    float h0  = tzero ? 0.f : halting[pos];
    float rem = tzero ? 0.f : remainders[pos];
    float nup = tzero ? 0.f : n_updates[pos];
    float still = (h0 < 1.0f) ? 1.f : 0.f;
    float cand  = h0 + p * still;
    float nh  = ((cand >  THRESH) ? 1.f : 0.f) * still;
    float st2 = ((cand <= THRESH) ? 1.f : 0.f) * still;
    h0  += p * st2;
    rem += nh * (1.0f - h0);
    h0  += nh * rem;
    nup += st2 + nh;
    float uwv = p * st2 + nh * rem;
    halting[pos]    = h0;
    remainders[pos] = rem;
    n_updates[pos]  = nup;
    uw_c[i]         = uwv;
  }
}

// ---- stage_x: x = st+te+pe (gathered) into single fp16 fragment plane -----
__global__ __launch_bounds__(256) void stagex_kernel(
    const float* __restrict__ st, const float* __restrict__ te,
    const float* __restrict__ pe_t, unsigned short* __restrict__ xf,
    const int* __restrict__ idxbuf, const int* __restrict__ cntp,
    int m_base, int mrows)
{
  const int K32 = Hh / 32;
  int cnt = *cntp;
  int rel = cnt - m_base;
  if (rel <= 0) return;
  if (rel > mrows) rel = mrows;
  int rows_pad = (rel + 127) & ~127;
  if (rows_pad > mrows) rows_pad = mrows;
  int id = blockIdx.x * 256 + threadIdx.x;
  int l = id & 63;
  int f = id >> 6;
  int mtile = f / K32, k0 = f - mtile * K32;
  if (mtile * 16 >= rows_pad) return;
  int m = m_base + mtile * 16 + (l & 15);
  int mc = (m < cnt) ? m : cnt - 1;
  int pos = idxbuf[mc];
  int kb = k0 * 32 + (l >> 4) * 8;
  const float* ap = st + (size_t)pos * Hh + kb;
  const float* tp = te + (size_t)(pos & (Ss - 1)) * Hh + kb;
  const float* pp = pe_t + kb;
  float4 xa = *(const float4*)ap, xb = *(const float4*)(ap + 4);
  float4 ta = *(const float4*)tp, tb = *(const float4*)(tp + 4);
  float4 pa = *(const float4*)pp, pb = *(const float4*)(pp + 4);
  float xs[8];
  xs[0] = xa.x + ta.x + pa.x; xs[1] = xa.y + ta.y + pa.y;
  xs[2] = xa.z + ta.z + pa.z; xs[3] = xa.w + ta.w + pa.w;
  xs[4] = xb.x + tb.x + pb.x; xs[5] = xb.y + tb.y + pb.y;
  xs[6] = xb.z + tb.z + pb.z; xs[7] = xb.w + tb.w + pb.w;
  split8_store1(xs, xf + ((size_t)f * 64 + l) * 8);
}

// ======================= GEMM kernels (A-LDS paired, B-direct) =============
// block 128x128, 4 waves (2m x 2n), wave 64x64 = 4x4 frags of 16x16x32 fp16.
// R16: k-steps in PAIRS. Per super-iter: stage 2 A-slabs (4 gloads/wave DMA)
// + prefetch B-pair (8 half8, ping-pong regs), vmcnt(12) waits only the
// PREVIOUS pair, ONE barrier, then 8 ds_read + 32 MFMA per wave. Rendezvous
// frequency per MFMA halves vs R13. RING-3 of pair-buffers (3 x 16 KB =
// 48 KB -> 3 blocks/CU). Reuse safety: buf staged at super-iter s was last
// read at s-2; those reads complete before any wave passes barrier s-1
// (MFMA consumption forces lgkmcnt drain) -- same argument as R9/R13.

// ---- GEMM1: h = relu(x @ w1 + b1), stored as single fp16 A-frag plane -----
#define LSTR 66
__global__ __launch_bounds__(256, 3) void gemm1_kernel(
    const unsigned short* __restrict__ xf, const unsigned short* __restrict__ w1f,
    const float* __restrict__ b1, unsigned short* __restrict__ hf,
    const int* __restrict__ cntp, int m_base)
{
  __shared__ __align__(1024) char stage[3 * BUFP];
  const int K32 = Hh / 32, NTOT = DFF / 16;   // 16, 128
  const int PAIRS = K32 / 2;                  // 8
  int lin = blockIdx.x;
  int gsz = gridDim.x;
  int q = gsz >> 3, r = gsz & 7;
  int xcd = lin & 7, idx0 = lin >> 3;
  int swz = (xcd < r) ? (xcd * (q + 1) + idx0)
                      : (r * (q + 1) + (xcd - r) * q + idx0);
  int strip = swz >> 4;
  int nb    = swz & 15;
  int cnt = *cntp;
  int m0 = strip * 128;
  if (m_base + m0 >= cnt) return;
  int tid = threadIdx.x, lane = tid & 63, w = tid >> 6;
  int wm = w >> 1, wn = w & 1;
  int n0 = nb * 128;
  int mtb0 = m0 >> 4, ntb0 = n0 >> 4;
  char* sptr = stage;

  // stage one k-PAIR: 16 tile-slots (2 slabs x 8 tiles), 4 gloads/wave
  auto stageP = [&](int bsel, int pr) {
    unsigned so = (unsigned)bsel * (unsigned)BUFP;
    int kk = pr * 2;
#pragma unroll
    for (int j = 0; j < 4; ++j) {
      int slab = j >> 1;
      int u = w * 2 + (j & 1);
      const unsigned short* g =
          xf + ((size_t)(mtb0 + u) * K32 + kk + slab) * 512 + (size_t)lane * 8;
      gload16(g, sptr + so + (unsigned)(slab * 8192 + u * 1024));
    }
  };
  auto loadBpair = [&](half8 (&b)[8], int pr) {
    int kk = pr * 2;
#pragma unroll
    for (int sl = 0; sl < 2; ++sl)
#pragma unroll
      for (int nt = 0; nt < 4; ++nt)
        b[sl * 4 + nt] = *(const half8*)(w1f +
            ((size_t)(kk + sl) * NTOT + (ntb0 + wn * 4 + nt)) * 512 +
            (size_t)lane * 8);
  };

  floatx4 am[4][4];
#pragma unroll
  for (int i = 0; i < 4; ++i)
#pragma unroll
    for (int j = 0; j < 4; ++j) am[i][j] = (floatx4){0.f, 0.f, 0.f, 0.f};

  half8 bP[8], bQ[8];
  stageP(0, 0);
  loadBpair(bP, 0);

  auto iter = [&](int s, int cur, half8 (&bu)[8], half8 (&bl)[8]) -> int {
    int nxt = (cur == 2) ? 0 : cur + 1;
    if (s + 1 < PAIRS) {
      stageP(nxt, s + 1);
      loadBpair(bl, s + 1);
      asm volatile("s_waitcnt vmcnt(12)" ::: "memory"); // pair(s) landed
    } else {
      asm volatile("s_waitcnt vmcnt(0)" ::: "memory");
    }
    __builtin_amdgcn_s_barrier();        // all waves' A-stage writes visible
    asm volatile("" ::: "memory");
    const char* sb = sptr + cur * BUFP + (size_t)lane * 16;
    half8 af0[4], af1[4];
#pragma unroll
    for (int mt = 0; mt < 4; ++mt) {
      af0[mt] = *(const half8*)(sb + (wm * 4 + mt) * 1024);
      af1[mt] = *(const half8*)(sb + 8192 + (wm * 4 + mt) * 1024);
    }
    __builtin_amdgcn_s_setprio(1);
#pragma unroll
    for (int mt = 0; mt < 4; ++mt)
#pragma unroll
      for (int nt = 0; nt < 4; ++nt)
        am[mt][nt] = __builtin_amdgcn_mfma_f32_16x16x32_f16(af0[mt], bu[nt],
                                                            am[mt][nt], 0, 0, 0);
#pragma unroll
    for (int mt = 0; mt < 4; ++mt)
#pragma unroll
      for (int nt = 0; nt < 4; ++nt)
        am[mt][nt] = __builtin_amdgcn_mfma_f32_16x16x32_f16(af1[mt], bu[4 + nt],
                                                            am[mt][nt], 0, 0, 0);
    __builtin_amdgcn_s_setprio(0);
    asm volatile("" ::: "memory");
    return nxt;
  };

  int cur = 0;
  for (int s = 0; s < PAIRS; s += 2) {   // PAIRS even
    cur = iter(s,     cur, bP, bQ);
    cur = iter(s + 1, cur, bQ, bP);
  }
  __syncthreads();   // final-iter readers done before epilogue reuses stage
  // epilogue: relu + bias; repack C-frag -> A-frag in 16-row slices.
  // Per-wave private LDS slice (4 x 4.2 KB = 16.9 KB <= 48 KB stage).
  {
    int r0 = (lane >> 4) * 4;
    int c0l = lane & 15;
    int mtb = mtb0 + wm * 4;
    int k2b = (n0 >> 5) + wn * 2;
    float* L = (float*)(void*)sptr + (size_t)w * (16 * LSTR);
    float bias[4];
#pragma unroll
    for (int nt = 0; nt < 4; ++nt) bias[nt] = b1[n0 + wn * 64 + nt * 16 + c0l];
#pragma unroll
    for (int mt = 0; mt < 4; ++mt) {
#pragma unroll
      for (int nt = 0; nt < 4; ++nt)
#pragma unroll
        for (int reg = 0; reg < 4; ++reg)
          L[(r0 + reg) * LSTR + nt * 16 + c0l] =
              fmaxf(am[mt][nt][reg] + bias[nt], 0.f);
#pragma unroll
      for (int k2 = 0; k2 < 2; ++k2) {
        const float* rp = L + (lane & 15) * LSTR + k2 * 32 + (lane >> 4) * 8;
        float xs[8];
        float4 xa = *(const float4*)rp, xb = *(const float4*)(rp + 4);
        xs[0]=xa.x; xs[1]=xa.y; xs[2]=xa.z; xs[3]=xa.w;
        xs[4]=xb.x; xs[5]=xb.y; xs[6]=xb.z; xs[7]=xb.w;
        size_t f2 = (size_t)(mtb + mt) * 64 + (k2b + k2);
        split8_store1(xs, hf + (f2 * 64 + lane) * 8);
      }
    }
  }
}

// ---- GEMM2f (FULL-K, paired, fused bias + uw-blend scatter) ---------------
__global__ __launch_bounds__(256, 3) void gemm2f_kernel(
    const unsigned short* __restrict__ hf, const unsigned short* __restrict__ w2f,
    const float* __restrict__ b2, const float* __restrict__ uw_c,
    float* __restrict__ st_out, float* __restrict__ prev,
    const int* __restrict__ idxbuf, const int* __restrict__ cntp,
    int m_base, int tzero)
{
  __shared__ __align__(1024) char stage[3 * BUFP];
  const int K32 = DFF / 32, NTOT = Hh / 16;   // 64, 32
  const int PAIRS = K32 / 2;                  // 32
  int lin = blockIdx.x;
  int gsz = gridDim.x;
  int q = gsz >> 3, r = gsz & 7;
  int xcd = lin & 7, idx0 = lin >> 3;
  int swz = (xcd < r) ? (xcd * (q + 1) + idx0)
                      : (r * (q + 1) + (xcd - r) * q + idx0);
  int strip = swz >> 2, nb = swz & 3;
  int cnt = *cntp;
  int m0 = strip * 128;
  if (m_base + m0 >= cnt) return;
  int n0 = nb * 128;
  int tid = threadIdx.x, lane = tid & 63, w = tid >> 6;
  int wm = w >> 1, wn = w & 1;
  int mtb0 = m0 >> 4, ntb0 = n0 >> 4;
  char* sptr = stage;

  auto stageP = [&](int bsel, int pr) {
    unsigned so = (unsigned)bsel * (unsigned)BUFP;
    int kk = pr * 2;
#pragma unroll
    for (int j = 0; j < 4; ++j) {
      int slab = j >> 1;
      int u = w * 2 + (j & 1);
      const unsigned short* g =
          hf + ((size_t)(mtb0 + u) * K32 + kk + slab) * 512 + (size_t)lane * 8;
      gload16(g, sptr + so + (unsigned)(slab * 8192 + u * 1024));
    }
  };
  auto loadBpair = [&](half8 (&b)[8], int pr) {
    int kk = pr * 2;
#pragma unroll
    for (int sl = 0; sl < 2; ++sl)
#pragma unroll
      for (int nt = 0; nt < 4; ++nt)
        b[sl * 4 + nt] = *(const half8*)(w2f +
            ((size_t)(kk + sl) * NTOT + (ntb0 + wn * 4 + nt)) * 512 +
            (size_t)lane * 8);
  };

  floatx4 am[4][4];
#pragma unroll
  for (int i = 0; i < 4; ++i)
#pragma unroll
    for (int j = 0; j < 4; ++j) am[i][j] = (floatx4){0.f, 0.f, 0.f, 0.f};

  half8 bP[8], bQ[8];
  stageP(0, 0);
  loadBpair(bP, 0);

  auto iter = [&](int s, int cur, half8 (&bu)[8], half8 (&bl)[8]) -> int {
    int nxt = (cur == 2) ? 0 : cur + 1;
    if (s + 1 < PAIRS) {
      stageP(nxt, s + 1);
      loadBpair(bl, s + 1);
      asm volatile("s_waitcnt vmcnt(12)" ::: "memory");
    } else {
      asm volatile("s_waitcnt vmcnt(0)" ::: "memory");
    }
    __builtin_amdgcn_s_barrier();
    asm volatile("" ::: "memory");
    const char* sb = sptr + cur * BUFP + (size_t)lane * 16;
    half8 af0[4], af1[4];
#pragma unroll
    for (int mt = 0; mt < 4; ++mt) {
      af0[mt] = *(const half8*)(sb + (wm * 4 + mt) * 1024);
      af1[mt] = *(const half8*)(sb + 8192 + (wm * 4 + mt) * 1024);
    }
#pragma unroll
    for (int mt = 0; mt < 4; ++mt)
#pragma unroll
      for (int nt = 0; nt < 4; ++nt)
        am[mt][nt] = __builtin_amdgcn_mfma_f32_16x16x32_f16(af0[mt], bu[nt],
                                                            am[mt][nt], 0, 0, 0);
#pragma unroll
    for (int mt = 0; mt < 4; ++mt)
#pragma unroll
      for (int nt = 0; nt < 4; ++nt)
        am[mt][nt] = __builtin_amdgcn_mfma_f32_16x16x32_f16(af1[mt], bu[4 + nt],
                                                            am[mt][nt], 0, 0, 0);
    asm volatile("" ::: "memory");
    return nxt;
  };

  int cur = 0;
  for (int s = 0; s < PAIRS; s += 2) {   // PAIRS even
    cur = iter(s,     cur, bP, bQ);
    cur = iter(s + 1, cur, bQ, bP);
  }
  // fused epilogue: sv = am + b2; st_out = sv; prev = sv*uw + prev*(1-uw)
  {
    int r0 = (lane >> 4) * 4;
    int c0l = lane & 15;
    int mtb = mtb0 + wm * 4;
    int njb = ntb0 + wn * 4;
    float bias[4];
#pragma unroll
    for (int nt = 0; nt < 4; ++nt) bias[nt] = b2[(njb + nt) * 16 + c0l];
#pragma unroll
    for (int mt = 0; mt < 4; ++mt) {
      int pos4[4]; float uw4[4]; bool ok4[4];
#pragma unroll
      for (int reg = 0; reg < 4; ++reg) {
        int m = m_base + (mtb + mt) * 16 + r0 + reg;
        ok4[reg] = (m < cnt);
        int mc = ok4[reg] ? m : 0;
        pos4[reg] = idxbuf[mc];
        uw4[reg]  = uw_c[mc];
      }
#pragma unroll
      for (int nt = 0; nt < 4; ++nt) {
        int col = (njb + nt) * 16 + c0l;
#pragma unroll
        for (int reg = 0; reg < 4; ++reg) {
          if (ok4[reg]) {
            float sv = am[mt][nt][reg] + bias[nt];
            size_t off = (size_t)pos4[reg] * Hh + col;
            float pv = tzero ? 0.f : prev[off];
            st_out[off] = sv;
            prev[off] = sv * uw4[reg] + pv * (1.f - uw4[reg]);
          }
        }
      }
    }
  }
}

extern "C" void kernel_launch(void* const* d_in, const int* in_sizes, int n_in,
                              void* d_out, int out_size, void* d_ws, size_t ws_size,
                              hipStream_t stream) {
  const float* state  = (const float*)d_in[0];
  const float* te     = (const float*)d_in[2];
  const float* pe     = (const float*)d_in[3];
  const float* wp     = (const float*)d_in[4];
  const float* bp     = (const float*)d_in[5];
  const float* w1     = (const float*)d_in[6];
  const float* b1     = (const float*)d_in[7];
  const float* w2     = (const float*)d_in[8];
  const float* b2     = (const float*)d_in[9];

  float* out        = (float*)d_out;
  float* prev       = out;                          // BS*H (fully written @t0)
  float* remainders = out + (size_t)BS * Hh;        // BS   (fully written @t0)
  float* n_updates  = remainders + BS;              // BS   (fully written @t0)

  float*          st      = (float*)d_ws;           // BS*H (fully written @t0)
  float*          halting = st + (size_t)BS * Hh;   // BS   (fully written @t0)
  float*          uw_c    = halting + BS;           // BS
  int*            idxbuf  = (int*)(uw_c + BS);      // BS
  int*            cntp    = idxbuf + BS;            // 64 (one counter per hop)
  unsigned short* w1f     = (unsigned short*)(cntp + 64);   // PS (2 MB)
  unsigned short* w2f     = w1f + (size_t)PS;               // PS (2 MB)
  unsigned short* hf      = w2f + (size_t)PS;

  size_t fixed = (size_t)((char*)hf - (char*)d_ws);
  size_t avail = (ws_size > fixed) ? (ws_size - fixed) : 0;
  // per row: hf = 2048*2 = 4096 B ; xf = 512*2 = 1024 B (single fp16 planes)
  int hrows = (int)((avail / 5120) & ~(size_t)127);
  if (hrows > BS) hrows = BS;
  if (hrows < 128) hrows = 128;
  unsigned short* xf = hf + (size_t)hrows * DFF;    // hf = hrows*DFF ushorts
  int nst = hrows / 128;

  // Only the hop counters need zeroing: all other state buffers are fully
  // written at hop 0 via the tzero paths.
  hipMemsetAsync(cntp, 0, 64 * sizeof(int), stream);

  prep_kernel<<<512, 256, 0, stream>>>(w1, w1f, Hh / 32, DFF / 16, DFF);
  prep_kernel<<<512, 256, 0, stream>>>(w2, w2f, DFF / 32, Hh / 16, Hh);

  for (int t = 0; t < HOPS; ++t) {
    const float* pe_t = pe + (size_t)t * Hh;
    int* cnt_t = cntp + t;
    int tz = (t == 0) ? 1 : 0;
    const float* st_src = tz ? state : st;   // hop 0 reads the input directly
    compact_kernel<<<BS / 1024, 1024, 0, stream>>>(halting, idxbuf, cnt_t, tz);
    halt_kernel<<<BS / 4, 256, 0, stream>>>(st_src, te, pe_t, wp, bp, halting,
                                            remainders, n_updates, uw_c,
                                            idxbuf, cnt_t, tz);
    for (int mb = 0; mb < BS; mb += hrows) {
      stagex_kernel<<<hrows / 4, 256, 0, stream>>>(st_src, te, pe_t, xf, idxbuf,
                                                   cnt_t, mb, hrows);
      gemm1_kernel<<<nst * 16, 256, 0, stream>>>(xf, w1f, b1, hf, cnt_t, mb);
      gemm2f_kernel<<<nst * 4, 256, 0, stream>>>(hf, w2f, b2, uw_c, st, prev,
                                                 idxbuf, cnt_t, mb, tz);
    }
  }
}

// Round 17
// 566.200 us; speedup vs baseline: 1.3038x; 1.3038x over previous
//
#include <hip/hip_runtime.h>
#include <math.h>

typedef short short8 __attribute__((ext_vector_type(8)));
typedef _Float16 half8 __attribute__((ext_vector_type(8)));
typedef float floatx4 __attribute__((ext_vector_type(4)));

#define Bb 64
#define Ss 512
#define Hh 512
#define DFF 2048
#define HOPS 6
#define BS (Bb*Ss)          // 32768 positions
#define PS 1048576          // weight plane stride (elems)
#define BUFA 8192           // A-only stage buffer (8 tiles x 1KB)

// ---------------- fp16 pack helpers ---------------------------------------
// ALL operands single fp16 plane. Error ledger (independent terms,
// quadrature-combined, vs observed floor absmax=0.0078):
//   h-rounding (R7):   ~3.4e-4  -- accepted, absmax 0.0039->0.0078
//   W2-rounding (R10): ~3.4e-4  -- accepted, absmax unchanged
//   W1-rounding (R11): ~2.0e-4  -- accepted, absmax unchanged
// R14 lesson: direct-VGPR loads (no LDS DMA, no barrier) REGRESSED 30% --
// global_load_lds fire-and-forget + counted vmcnt is the enabler, not the
// cost. R16 lesson: k-step pairing regressed 35% (B-reg pressure).
// This file is the exact R13/R15 structure (measured best, ~567 us).
__device__ inline unsigned short f16u(float v) {
  _Float16 h = (_Float16)v;
  union { _Float16 h; unsigned short u; } c; c.h = h; return c.u;
}
__device__ inline void split8_store1(const float* xs, unsigned short* dst) {
  unsigned q[4];
#pragma unroll
  for (int j = 0; j < 4; ++j)
    q[j] = (unsigned)f16u(xs[2*j]) | ((unsigned)f16u(xs[2*j+1]) << 16);
  *(int4*)dst = make_int4(q[0], q[1], q[2], q[3]);
}

// ---------------- async global->LDS 16B helper -----------------------------
__device__ __forceinline__ void gload16(const void* g, void* l) {
  __builtin_amdgcn_global_load_lds(
      (const __attribute__((address_space(1))) void*)g,
      (__attribute__((address_space(3))) void*)l, 16, 0, 0);
}

// ---------------- weight pre-split into fragment-linear fp16 planes -------
__global__ __launch_bounds__(256) void prep_kernel(
    const float* __restrict__ w, unsigned short* __restrict__ wf,
    int K32, int NTOT, int N)
{
  int id = blockIdx.x * 256 + threadIdx.x;      // one per (k0,NT,lane)
  if (id >= K32 * NTOT * 64) return;
  int l  = id & 63;
  int NT = (id >> 6) % NTOT;
  int k0 = id / (64 * NTOT);
  int n  = NT * 16 + (l & 15);
  int kb = k0 * 32 + 8 * (l >> 4);
  float xs[8];
#pragma unroll
  for (int j = 0; j < 8; ++j) xs[j] = w[(size_t)(kb + j) * N + n];
  split8_store1(xs, wf + (size_t)id * 8);
}

// ---------------- parallel compaction (order-free, outputs invariant) ------
__global__ __launch_bounds__(1024) void compact_kernel(
    const float* __restrict__ halting, int* __restrict__ idx,
    int* __restrict__ cnt, int tzero)
{
  __shared__ int wsum[16];
  __shared__ int wbase[16];
  __shared__ int s_base;
  int tid = threadIdx.x;
  int lane = tid & 63, wid = tid >> 6;
  int pos = blockIdx.x * 1024 + tid;
  int flag = tzero ? 1 : ((halting[pos] < 1.0f) ? 1 : 0);
  unsigned long long m = __ballot(flag);
  int pre = __popcll(m & ((1ull << lane) - 1ull));
  if (lane == 0) wsum[wid] = __popcll(m);
  __syncthreads();
  if (tid == 0) {
    int a = 0;
#pragma unroll
    for (int i = 0; i < 16; ++i) { wbase[i] = a; a += wsum[i]; }
    s_base = (a > 0) ? atomicAdd(cnt, a) : 0;
  }
  __syncthreads();
  if (flag) idx[s_base + wbase[wid] + pre] = pos;
}

// ---------------- halting / p kernel (pure fp32) ---------------------------
__global__ __launch_bounds__(256) void halt_kernel(
    const float* __restrict__ st, const float* __restrict__ te,
    const float* __restrict__ pe_t, const float* __restrict__ wp,
    const float* __restrict__ bp, float* __restrict__ halting,
    float* __restrict__ remainders, float* __restrict__ n_updates,
    float* __restrict__ uw_c, const int* __restrict__ idxbuf,
    const int* __restrict__ cntp, int tzero)
{
  int cnt = *cntp;
  int i = blockIdx.x * 4 + (threadIdx.x >> 6);
  if (i >= cnt) return;
  int lane = threadIdx.x & 63;
  int pos = idxbuf[i];
  int s = pos & (Ss - 1);
  const float4* stv = (const float4*)(st + (size_t)pos * Hh);
  const float4* tev = (const float4*)(te + (size_t)s * Hh);
  const float4* pev = (const float4*)pe_t;
  const float4* wpv = (const float4*)wp;
  float sum = 0.f;
#pragma unroll
  for (int j = 0; j < 2; ++j) {
    int idx = lane + j * 64;
    float4 a = stv[idx], b = tev[idx], c = pev[idx], w = wpv[idx];
    sum += (a.x + b.x + c.x) * w.x + (a.y + b.y + c.y) * w.y +
           (a.z + b.z + c.z) * w.z + (a.w + b.w + c.w) * w.w;
  }
#pragma unroll
  for (int off = 32; off > 0; off >>= 1) sum += __shfl_xor(sum, off, 64);
  if (lane == 0) {
    float y = sum + bp[0];
    float p = 1.0f / (1.0f + expf(-y));
    const float THRESH = 1.0f - 0.1f;
    float h0  = tzero ? 0.f : halting[pos];
    float rem = tzero ? 0.f : remainders[pos];
    float nup = tzero ? 0.f : n_updates[pos];
    float still = (h0 < 1.0f) ? 1.f : 0.f;
    float cand  = h0 + p * still;
    float nh  = ((cand >  THRESH) ? 1.f : 0.f) * still;
    float st2 = ((cand <= THRESH) ? 1.f : 0.f) * still;
    h0  += p * st2;
    rem += nh * (1.0f - h0);
    h0  += nh * rem;
    nup += st2 + nh;
    float uwv = p * st2 + nh * rem;
    halting[pos]    = h0;
    remainders[pos] = rem;
    n_updates[pos]  = nup;
    uw_c[i]         = uwv;
  }
}

// ---- stage_x: x = st+te+pe (gathered) into single fp16 fragment plane -----
__global__ __launch_bounds__(256) void stagex_kernel(
    const float* __restrict__ st, const float* __restrict__ te,
    const float* __restrict__ pe_t, unsigned short* __restrict__ xf,
    const int* __restrict__ idxbuf, const int* __restrict__ cntp,
    int m_base, int mrows)
{
  const int K32 = Hh / 32;
  int cnt = *cntp;
  int rel = cnt - m_base;
  if (rel <= 0) return;
  if (rel > mrows) rel = mrows;
  int rows_pad = (rel + 127) & ~127;
  if (rows_pad > mrows) rows_pad = mrows;
  int id = blockIdx.x * 256 + threadIdx.x;
  int l = id & 63;
  int f = id >> 6;
  int mtile = f / K32, k0 = f - mtile * K32;
  if (mtile * 16 >= rows_pad) return;
  int m = m_base + mtile * 16 + (l & 15);
  int mc = (m < cnt) ? m : cnt - 1;
  int pos = idxbuf[mc];
  int kb = k0 * 32 + (l >> 4) * 8;
  const float* ap = st + (size_t)pos * Hh + kb;
  const float* tp = te + (size_t)(pos & (Ss - 1)) * Hh + kb;
  const float* pp = pe_t + kb;
  float4 xa = *(const float4*)ap, xb = *(const float4*)(ap + 4);
  float4 ta = *(const float4*)tp, tb = *(const float4*)(tp + 4);
  float4 pa = *(const float4*)pp, pb = *(const float4*)(pp + 4);
  float xs[8];
  xs[0] = xa.x + ta.x + pa.x; xs[1] = xa.y + ta.y + pa.y;
  xs[2] = xa.z + ta.z + pa.z; xs[3] = xa.w + ta.w + pa.w;
  xs[4] = xb.x + tb.x + pb.x; xs[5] = xb.y + tb.y + pb.y;
  xs[6] = xb.z + tb.z + pb.z; xs[7] = xb.w + tb.w + pb.w;
  split8_store1(xs, xf + ((size_t)f * 64 + l) * 8);
}

// ======================= GEMM kernels (A-LDS, B-direct) ====================
// block 128x128, 4 waves (2m x 2n), wave 64x64 = 4x4 frags of 16x16x32 fp16.
// R13 structure (measured best): B (weights, 2 MB, L2-resident) loaded
// DIRECTLY to registers per wave (4 half8 loads, ping-pong prefetched 1 iter
// ahead); LDS stages A only via global_load_lds DMA (8 KB/buf, ring-3 =
// 24 KB -> 3 blocks/CU). vmcnt(6) before the barrier leaves exactly
// stage(k+1)+B(k+1) in flight and drains B(k)+stage(k). One barrier per
// k-step (ring-3 reuse argument, R9-verified).

// ---- GEMM1: h = relu(x @ w1 + b1), stored as single fp16 A-frag plane -----
#define LSTR 66
__global__ __launch_bounds__(256, 3) void gemm1_kernel(
    const unsigned short* __restrict__ xf, const unsigned short* __restrict__ w1f,
    const float* __restrict__ b1, unsigned short* __restrict__ hf,
    const int* __restrict__ cntp, int m_base)
{
  __shared__ __align__(1024) char stage[3 * BUFA];
  const int K32 = Hh / 32, NTOT = DFF / 16;   // 16, 128
  int lin = blockIdx.x;
  int gsz = gridDim.x;
  int q = gsz >> 3, r = gsz & 7;
  int xcd = lin & 7, idx0 = lin >> 3;
  int swz = (xcd < r) ? (xcd * (q + 1) + idx0)
                      : (r * (q + 1) + (xcd - r) * q + idx0);
  int strip = swz >> 4;
  int nb    = swz & 15;
  int cnt = *cntp;
  int m0 = strip * 128;
  if (m_base + m0 >= cnt) return;
  int tid = threadIdx.x, lane = tid & 63, w = tid >> 6;
  int wm = w >> 1, wn = w & 1;
  int n0 = nb * 128;
  int mtb0 = m0 >> 4, ntb0 = n0 >> 4;
  char* sptr = stage;

  auto stageA = [&](int bsel, int kk) {
    unsigned so = (unsigned)bsel * (unsigned)BUFA;
#pragma unroll
    for (int j = 0; j < 2; ++j) {
      int u = w * 2 + j;
      const unsigned short* g =
          xf + ((size_t)(mtb0 + u) * K32 + kk) * 512 + (size_t)lane * 8;
      gload16(g, sptr + so + (unsigned)u * 1024u);
    }
  };
  auto loadB = [&](half8 (&b)[4], int kk) {
#pragma unroll
    for (int nt = 0; nt < 4; ++nt)
      b[nt] = *(const half8*)(w1f +
          ((size_t)kk * NTOT + (ntb0 + wn * 4 + nt)) * 512 + (size_t)lane * 8);
  };

  floatx4 am[4][4];
#pragma unroll
  for (int i = 0; i < 4; ++i)
#pragma unroll
    for (int j = 0; j < 4; ++j) am[i][j] = (floatx4){0.f, 0.f, 0.f, 0.f};

  half8 bfA[4], bfB[4];
  stageA(0, 0);
  loadB(bfA, 0);

  auto iter = [&](int k, int cur, half8 (&bu)[4], half8 (&bl)[4]) -> int {
    int nxt = (cur == 2) ? 0 : cur + 1;
    if (k + 1 < K32) {
      stageA(nxt, k + 1);
      loadB(bl, k + 1);
      asm volatile("s_waitcnt vmcnt(6)" ::: "memory"); // stage(k)+B(k) landed
    } else {
      asm volatile("s_waitcnt vmcnt(0)" ::: "memory");
    }
    __builtin_amdgcn_s_barrier();        // all waves' A-stage writes visible
    asm volatile("" ::: "memory");
    const char* sb = sptr + cur * BUFA + (size_t)lane * 16;
    half8 af[4];
#pragma unroll
    for (int mt = 0; mt < 4; ++mt)
      af[mt] = *(const half8*)(sb + (wm * 4 + mt) * 1024);
    __builtin_amdgcn_s_setprio(1);
#pragma unroll
    for (int mt = 0; mt < 4; ++mt)
#pragma unroll
      for (int nt = 0; nt < 4; ++nt)
        am[mt][nt] = __builtin_amdgcn_mfma_f32_16x16x32_f16(af[mt], bu[nt],
                                                            am[mt][nt], 0, 0, 0);
    __builtin_amdgcn_s_setprio(0);
    asm volatile("" ::: "memory");
    return nxt;
  };

  int cur = 0;
  for (int k0 = 0; k0 < K32; k0 += 2) {   // K32 even
    cur = iter(k0,     cur, bfA, bfB);
    cur = iter(k0 + 1, cur, bfB, bfA);
  }
  __syncthreads();   // final-iter readers done before epilogue reuses stage
  // epilogue: relu + bias; repack C-frag -> A-frag in 16-row slices.
  // Per-wave private LDS slice (4 x 4.2 KB = 16.9 KB <= 24 KB stage).
  {
    int r0 = (lane >> 4) * 4;
    int c0l = lane & 15;
    int mtb = mtb0 + wm * 4;
    int k2b = (n0 >> 5) + wn * 2;
    float* L = (float*)(void*)sptr + (size_t)w * (16 * LSTR);
    float bias[4];
#pragma unroll
    for (int nt = 0; nt < 4; ++nt) bias[nt] = b1[n0 + wn * 64 + nt * 16 + c0l];
#pragma unroll
    for (int mt = 0; mt < 4; ++mt) {
#pragma unroll
      for (int nt = 0; nt < 4; ++nt)
#pragma unroll
        for (int reg = 0; reg < 4; ++reg)
          L[(r0 + reg) * LSTR + nt * 16 + c0l] =
              fmaxf(am[mt][nt][reg] + bias[nt], 0.f);
#pragma unroll
      for (int k2 = 0; k2 < 2; ++k2) {
        const float* rp = L + (lane & 15) * LSTR + k2 * 32 + (lane >> 4) * 8;
        float xs[8];
        float4 xa = *(const float4*)rp, xb = *(const float4*)(rp + 4);
        xs[0]=xa.x; xs[1]=xa.y; xs[2]=xa.z; xs[3]=xa.w;
        xs[4]=xb.x; xs[5]=xb.y; xs[6]=xb.z; xs[7]=xb.w;
        size_t f2 = (size_t)(mtb + mt) * 64 + (k2b + k2);
        split8_store1(xs, hf + (f2 * 64 + lane) * 8);
      }
    }
  }
}

// ---- GEMM2f (FULL-K, A-LDS/B-direct, fused bias + uw-blend scatter) -------
__global__ __launch_bounds__(256, 3) void gemm2f_kernel(
    const unsigned short* __restrict__ hf, const unsigned short* __restrict__ w2f,
    const float* __restrict__ b2, const float* __restrict__ uw_c,
    float* __restrict__ st_out, float* __restrict__ prev,
    const int* __restrict__ idxbuf, const int* __restrict__ cntp,
    int m_base, int tzero)
{
  __shared__ __align__(1024) char stage[3 * BUFA];
  const int K32 = DFF / 32, NTOT = Hh / 16;   // 64, 32
  int lin = blockIdx.x;
  int gsz = gridDim.x;
  int q = gsz >> 3, r = gsz & 7;
  int xcd = lin & 7, idx0 = lin >> 3;
  int swz = (xcd < r) ? (xcd * (q + 1) + idx0)
                      : (r * (q + 1) + (xcd - r) * q + idx0);
  int strip = swz >> 2, nb = swz & 3;
  int cnt = *cntp;
  int m0 = strip * 128;
  if (m_base + m0 >= cnt) return;
  int n0 = nb * 128;
  int tid = threadIdx.x, lane = tid & 63, w = tid >> 6;
  int wm = w >> 1, wn = w & 1;
  int mtb0 = m0 >> 4, ntb0 = n0 >> 4;
  char* sptr = stage;

  auto stageA = [&](int bsel, int kk) {
    unsigned so = (unsigned)bsel * (unsigned)BUFA;
#pragma unroll
    for (int j = 0; j < 2; ++j) {
      int u = w * 2 + j;
      const unsigned short* g =
          hf + ((size_t)(mtb0 + u) * K32 + kk) * 512 + (size_t)lane * 8;
      gload16(g, sptr + so + (unsigned)u * 1024u);
    }
  };
  auto loadB = [&](half8 (&b)[4], int kk) {
#pragma unroll
    for (int nt = 0; nt < 4; ++nt)
      b[nt] = *(const half8*)(w2f +
          ((size_t)kk * NTOT + (ntb0 + wn * 4 + nt)) * 512 + (size_t)lane * 8);
  };

  floatx4 am[4][4];
#pragma unroll
  for (int i = 0; i < 4; ++i)
#pragma unroll
    for (int j = 0; j < 4; ++j) am[i][j] = (floatx4){0.f, 0.f, 0.f, 0.f};

  half8 bfA[4], bfB[4];
  stageA(0, 0);
  loadB(bfA, 0);

  auto iter = [&](int k, int cur, half8 (&bu)[4], half8 (&bl)[4]) -> int {
    int nxt = (cur == 2) ? 0 : cur + 1;
    if (k + 1 < K32) {
      stageA(nxt, k + 1);
      loadB(bl, k + 1);
      asm volatile("s_waitcnt vmcnt(6)" ::: "memory");
    } else {
      asm volatile("s_waitcnt vmcnt(0)" ::: "memory");
    }
    __builtin_amdgcn_s_barrier();
    asm volatile("" ::: "memory");
    const char* sb = sptr + cur * BUFA + (size_t)lane * 16;
    half8 af[4];
#pragma unroll
    for (int mt = 0; mt < 4; ++mt)
      af[mt] = *(const half8*)(sb + (wm * 4 + mt) * 1024);
#pragma unroll
    for (int mt = 0; mt < 4; ++mt)
#pragma unroll
      for (int nt = 0; nt < 4; ++nt)
        am[mt][nt] = __builtin_amdgcn_mfma_f32_16x16x32_f16(af[mt], bu[nt],
                                                            am[mt][nt], 0, 0, 0);
    asm volatile("" ::: "memory");
    return nxt;
  };

  int cur = 0;
  for (int k0 = 0; k0 < K32; k0 += 2) {   // K32 even
    cur = iter(k0,     cur, bfA, bfB);
    cur = iter(k0 + 1, cur, bfB, bfA);
  }
  // fused epilogue: sv = am + b2; st_out = sv; prev = sv*uw + prev*(1-uw)
  {
    int r0 = (lane >> 4) * 4;
    int c0l = lane & 15;
    int mtb = mtb0 + wm * 4;
    int njb = ntb0 + wn * 4;
    float bias[4];
#pragma unroll
    for (int nt = 0; nt < 4; ++nt) bias[nt] = b2[(njb + nt) * 16 + c0l];
#pragma unroll
    for (int mt = 0; mt < 4; ++mt) {
      int pos4[4]; float uw4[4]; bool ok4[4];
#pragma unroll
      for (int reg = 0; reg < 4; ++reg) {
        int m = m_base + (mtb + mt) * 16 + r0 + reg;
        ok4[reg] = (m < cnt);
        int mc = ok4[reg] ? m : 0;
        pos4[reg] = idxbuf[mc];
        uw4[reg]  = uw_c[mc];
      }
#pragma unroll
      for (int nt = 0; nt < 4; ++nt) {
        int col = (njb + nt) * 16 + c0l;
#pragma unroll
        for (int reg = 0; reg < 4; ++reg) {
          if (ok4[reg]) {
            float sv = am[mt][nt][reg] + bias[nt];
            size_t off = (size_t)pos4[reg] * Hh + col;
            float pv = tzero ? 0.f : prev[off];
            st_out[off] = sv;
            prev[off] = sv * uw4[reg] + pv * (1.f - uw4[reg]);
          }
        }
      }
    }
  }
}

extern "C" void kernel_launch(void* const* d_in, const int* in_sizes, int n_in,
                              void* d_out, int out_size, void* d_ws, size_t ws_size,
                              hipStream_t stream) {
  const float* state  = (const float*)d_in[0];
  const float* te     = (const float*)d_in[2];
  const float* pe     = (const float*)d_in[3];
  const float* wp     = (const float*)d_in[4];
  const float* bp     = (const float*)d_in[5];
  const float* w1     = (const float*)d_in[6];
  const float* b1     = (const float*)d_in[7];
  const float* w2     = (const float*)d_in[8];
  const float* b2     = (const float*)d_in[9];

  float* out        = (float*)d_out;
  float* prev       = out;                          // BS*H (fully written @t0)
  float* remainders = out + (size_t)BS * Hh;        // BS   (fully written @t0)
  float* n_updates  = remainders + BS;              // BS   (fully written @t0)

  float*          st      = (float*)d_ws;           // BS*H (fully written @t0)
  float*          halting = st + (size_t)BS * Hh;   // BS   (fully written @t0)
  float*          uw_c    = halting + BS;           // BS
  int*            idxbuf  = (int*)(uw_c + BS);      // BS
  int*            cntp    = idxbuf + BS;            // 64 (one counter per hop)
  unsigned short* w1f     = (unsigned short*)(cntp + 64);   // PS (2 MB)
  unsigned short* w2f     = w1f + (size_t)PS;               // PS (2 MB)
  unsigned short* hf      = w2f + (size_t)PS;

  size_t fixed = (size_t)((char*)hf - (char*)d_ws);
  size_t avail = (ws_size > fixed) ? (ws_size - fixed) : 0;
  // per row: hf = 2048*2 = 4096 B ; xf = 512*2 = 1024 B (single fp16 planes)
  int hrows = (int)((avail / 5120) & ~(size_t)127);
  if (hrows > BS) hrows = BS;
  if (hrows < 128) hrows = 128;
  unsigned short* xf = hf + (size_t)hrows * DFF;    // hf = hrows*DFF ushorts
  int nst = hrows / 128;

  // Only the hop counters need zeroing: all other state buffers are fully
  // written at hop 0 via the tzero paths.
  hipMemsetAsync(cntp, 0, 64 * sizeof(int), stream);

  prep_kernel<<<512, 256, 0, stream>>>(w1, w1f, Hh / 32, DFF / 16, DFF);
  prep_kernel<<<512, 256, 0, stream>>>(w2, w2f, DFF / 32, Hh / 16, Hh);

  for (int t = 0; t < HOPS; ++t) {
    const float* pe_t = pe + (size_t)t * Hh;
    int* cnt_t = cntp + t;
    int tz = (t == 0) ? 1 : 0;
    const float* st_src = tz ? state : st;   // hop 0 reads the input directly
    compact_kernel<<<BS / 1024, 1024, 0, stream>>>(halting, idxbuf, cnt_t, tz);
    halt_kernel<<<BS / 4, 256, 0, stream>>>(st_src, te, pe_t, wp, bp, halting,
                                            remainders, n_updates, uw_c,
                                            idxbuf, cnt_t, tz);
    for (int mb = 0; mb < BS; mb += hrows) {
      stagex_kernel<<<hrows / 4, 256, 0, stream>>>(st_src, te, pe_t, xf, idxbuf,
                                                   cnt_t, mb, hrows);
      gemm1_kernel<<<nst * 16, 256, 0, stream>>>(xf, w1f, b1, hf, cnt_t, mb);
      gemm2f_kernel<<<nst * 4, 256, 0, stream>>>(hf, w2f, b2, uw_c, st, prev,
                                                 idxbuf, cnt_t, mb, tz);
    }
  }
}